// Round 7
// baseline (94.442 us; speedup 1.0000x reference)
//
#include <hip/hip_runtime.h>

#define NN 4096
#define DD 256
#define TEMP 0.07f
#define INV_T (1.0f / TEMP)
#define LOG2E 1.44269504089f
#define CEL (INV_T * LOG2E)      // el = exp2(s*CEL - CEL)
#define BLK 256
#define IB 64             // i-rows per block (4 tiles of 16)
#define JC 32             // j-chunks
#define JPC (NN / JC)     // 128 j per chunk: 4 waves x 2 tiles x 16
#define GRID ((NN / IB) * JC)   // 2048 blocks
#define M_E1 2.718281828f

typedef __attribute__((ext_vector_type(8))) short short8;
typedef __attribute__((ext_vector_type(4))) float f32x4;

__device__ __forceinline__ unsigned short f2bf(float x) {
    unsigned int b = __float_as_uint(x);
    return (unsigned short)((b + 0x7fffu + ((b >> 16) & 1u)) >> 16);
}

// ---------------- convert F f32 -> bf16; zero out ----------------
__global__ __launch_bounds__(256) void cvt_k(const float* __restrict__ F,
                                             unsigned short* __restrict__ Fb,
                                             float* __restrict__ out) {
    int idx = blockIdx.x * 256 + threadIdx.x;
    float4 v = ((const float4*)F)[idx];
    ushort4 o;
    o.x = f2bf(v.x); o.y = f2bf(v.y); o.z = f2bf(v.z); o.w = f2bf(v.w);
    ((ushort4*)Fb)[idx] = o;
    if (idx == 0) out[0] = 0.f;
}

// ---------------- single-pass stats kernel, 16x16x32 MFMA ----------------
// Per row i, 8 stats (l=(s-1)/T):
//   S=sum_all e^s, E=sum_{j!=i} e^l, T=sum_all e^l*e^s,
//   a=sum_same' e^s, f1=sum_same' e^l*e^s, g=sum_same' l, h=sum_same' l*e^s, c=|same'|
// finalize: b=S-a-e, f2=T-f1-e (self terms analytic).
__global__ __launch_bounds__(BLK, 4) void supcon_k(const unsigned short* __restrict__ Fb,
                                                   const int* __restrict__ labels,
                                                   float* __restrict__ partial) {
    __shared__ unsigned short sFi[IB * DD];   // 32 KB, 32-slot XOR swizzle
    __shared__ int slab[JPC];                 // 512 B
    float* sred = (float*)sFi;                // aliased after compute: [4][64][8]

    const int tid = threadIdx.x;
    const int lane = tid & 63;
    const int wid = tid >> 6;                 // 0..3
    const int il = lane & 15;                 // i-local within tile / A j-row within tile
    const int kg = lane >> 4;                 // 0..3 k-group
    const int ib = blockIdx.x >> 5;
    const int jc = blockIdx.x & (JC - 1);
    const int i0 = ib * IB;
    const int jb0 = jc * JPC + (wid * 2) * 16;      // tile 0
    const int jb1 = jb0 + 16;                        // tile 1

    // ---- tile-0 A-fragments first (fly during LDS staging) ----
    // A[row=il][k]: 16B at element k*32 + kg*8  (short8 units: row*32 + k*4 + kg)
    const short8* ap0 = (const short8*)Fb + (size_t)(jb0 + il) * 32 + kg;
    const short8* ap1 = (const short8*)Fb + (size_t)(jb1 + il) * 32 + kg;
    short8 af[8];
#pragma unroll
    for (int k = 0; k < 8; k++) af[k] = ap0[k * 4];

    // ---- stage i-rows into LDS, 32-slot XOR swizzle ----
    for (int idx = tid; idx < IB * 32; idx += BLK) {
        int row = idx >> 5, c16 = idx & 31;
        short8 v = *(const short8*)(Fb + (size_t)(i0 + row) * DD + c16 * 8);
        *(short8*)(&sFi[row * DD + ((c16 ^ (row & 31)) * 8)]) = v;
    }
    if (tid < JPC) slab[tid] = labels[jc * JPC + tid];
    int li[4];
#pragma unroll
    for (int it = 0; it < 4; it++) li[it] = labels[i0 + it * 16 + il];
    __syncthreads();

    const bool hasdiag = (jc == (i0 >> 7));
    float st[4][8];
#pragma unroll
    for (int it = 0; it < 4; it++)
#pragma unroll
        for (int k = 0; k < 8; k++) st[it][k] = 0.f;

#define KLOOP(ACC)                                                              \
    {                                                                           \
_Pragma("unroll")                                                               \
        for (int k = 0; k < 8; k++) {                                           \
_Pragma("unroll")                                                               \
            for (int it = 0; it < 4; it++) {                                    \
                int rb = it * 16 + il;                                          \
                int slot = (4 * k + kg) ^ (rb & 31);                            \
                short8 bf = *(const short8*)(&sFi[rb * DD + slot * 8]);         \
                ACC[it] = __builtin_amdgcn_mfma_f32_16x16x32_bf16(af[k], bf, ACC[it], 0, 0, 0); \
            }                                                                   \
        }                                                                       \
    }

#define EPILOGUE(ACC, JB)                                                       \
    {                                                                           \
_Pragma("unroll")                                                               \
        for (int r = 0; r < 4; r++) {                                           \
            const int jrow = kg * 4 + r;                                        \
            const int jg = (JB) + jrow;                                         \
            const int lj = slab[jg - jc * JPC];                                 \
_Pragma("unroll")                                                               \
            for (int it = 0; it < 4; it++) {                                    \
                float s = ACC[it][r];                                           \
                const int ig = i0 + it * 16 + il;                               \
                bool same = (lj == li[it]);                                     \
                bool self = hasdiag && (jg == ig);                              \
                float msf = (same && !self) ? 1.f : 0.f;                        \
                float nsf = self ? 0.f : 1.f;                                   \
                float l  = fmaf(s, INV_T, -INV_T);                              \
                float es = exp2f(s * LOG2E);                                    \
                float el = exp2f(fmaf(s, CEL, -CEL));                           \
                float t  = el * es;                                             \
                st[it][0] += es;                                                \
                st[it][1] = fmaf(nsf, el, st[it][1]);                           \
                st[it][2] += t;                                                 \
                st[it][3] = fmaf(msf, es, st[it][3]);                           \
                st[it][4] = fmaf(msf, t,  st[it][4]);                           \
                st[it][5] = fmaf(msf, l,  st[it][5]);                           \
                st[it][6] = fmaf(msf, l * es, st[it][6]);                       \
                st[it][7] += msf;                                               \
            }                                                                   \
        }                                                                       \
    }

    // ---- tile 0 ----
    f32x4 acc[4];
#pragma unroll
    for (int it = 0; it < 4; it++) acc[it] = (f32x4){0.f, 0.f, 0.f, 0.f};
    KLOOP(acc)

    // issue tile-1 A loads now (reuse af regs); epilogue below hides latency
#pragma unroll
    for (int k = 0; k < 8; k++) af[k] = ap1[k * 4];
    __builtin_amdgcn_sched_barrier(0);

    EPILOGUE(acc, jb0)

    asm volatile("" ::: "memory");   // block LDS-load CSE across tiles

    // ---- tile 1 ----
#pragma unroll
    for (int it = 0; it < 4; it++) acc[it] = (f32x4){0.f, 0.f, 0.f, 0.f};
    KLOOP(acc)
    EPILOGUE(acc, jb1)

    // ---- reduce over kg lanes (rows split across kg) ----
#pragma unroll
    for (int it = 0; it < 4; it++)
#pragma unroll
        for (int k = 0; k < 8; k++) {
            st[it][k] += __shfl_xor(st[it][k], 16, 64);
            st[it][k] += __shfl_xor(st[it][k], 32, 64);
        }

    __syncthreads();   // sFi reads done; alias as sred
    if (kg == 0) {
#pragma unroll
        for (int it = 0; it < 4; it++)
#pragma unroll
            for (int k = 0; k < 8; k++)
                sred[(wid * IB + it * 16 + il) * 8 + k] = st[it][k];
    }
    __syncthreads();
    {
        const int row = tid >> 2;           // 256 threads: 64 rows x 4...
        // 64 rows x 8 stats = 512 entries, 256 threads -> 2 each
        const int k2 = (tid & 3) * 2;
        float v0 = 0.f, v1 = 0.f;
#pragma unroll
        for (int w = 0; w < 4; w++) {
            v0 += sred[(w * IB + row) * 8 + k2];
            v1 += sred[(w * IB + row) * 8 + k2 + 1];
        }
        partial[((size_t)jc * NN + i0 + row) * 8 + k2] = v0;
        partial[((size_t)jc * NN + i0 + row) * 8 + k2 + 1] = v1;
    }
}

// ---------------- finalize: merge chunks, compute loss ----------------
__global__ __launch_bounds__(256) void finalize_k(const float* __restrict__ partial,
                                                  float* __restrict__ out) {
    __shared__ float sacc[4];
    const int t = threadIdx.x;
    const int i = blockIdx.x * 256 + t;

    float st[8];
#pragma unroll
    for (int k = 0; k < 8; k++) st[k] = 0.f;
    for (int jc = 0; jc < JC; jc++) {
        const float4* p = (const float4*)&partial[((size_t)jc * NN + i) * 8];
        float4 x = p[0], y = p[1];
        st[0] += x.x; st[1] += x.y; st[2] += x.z; st[3] += x.w;
        st[4] += y.x; st[5] += y.y; st[6] += y.z; st[7] += y.w;
    }
    float S = st[0], E = st[1], T = st[2], a = st[3];
    float f1 = st[4], g = st[5], h = st[6], c = st[7];
    float b = S - a - M_E1;
    float f2 = T - f1 - M_E1;
    float As = (a > 0.f) ? a : 1.f;
    float Bd = (b > 0.f) ? b : 1.f;
    float Z = E + f2 / Bd - f1 / As;
    float Q = g - h / As;
    float P = c - ((a > 0.f) ? 1.f : 0.f);
    float ms = (c > 0.f) ? c : 1.f;
    float loss_i = -(Q - P * logf(Z + 1e-8f)) / ms;

    float v = loss_i;
#pragma unroll
    for (int off = 32; off > 0; off >>= 1) v += __shfl_xor(v, off, 64);
    if ((t & 63) == 0) sacc[t >> 6] = v;
    __syncthreads();
    if (t == 0) atomicAdd(out, (sacc[0] + sacc[1] + sacc[2] + sacc[3]) * (1.0f / NN));
}

extern "C" void kernel_launch(void* const* d_in, const int* in_sizes, int n_in,
                              void* d_out, int out_size, void* d_ws, size_t ws_size,
                              hipStream_t stream) {
    const float* F = (const float*)d_in[0];
    const int* labels = (const int*)d_in[1];
    float* out = (float*)d_out;
    unsigned short* Fb = (unsigned short*)d_ws;                   // 2 MB
    float* partial = (float*)((char*)d_ws + (size_t)NN * DD * 2); // 4 MB (JC*NN*8 floats)

    cvt_k<<<NN * DD / 4 / 256, 256, 0, stream>>>(F, Fb, out);
    supcon_k<<<GRID, BLK, 0, stream>>>(Fb, labels, partial);
    finalize_k<<<NN / 256, 256, 0, stream>>>(partial, out);
}